// Round 8
// baseline (292.503 us; speedup 1.0000x reference)
//
#include <hip/hip_runtime.h>
#include <hip/hip_bf16.h>

typedef short bf16x8 __attribute__((ext_vector_type(8)));
typedef short short4v __attribute__((ext_vector_type(4)));
typedef float f32x4 __attribute__((ext_vector_type(4)));

__device__ __forceinline__ short f2b(float f) {
  __hip_bfloat16 h = __float2bfloat16(f);
  union { __hip_bfloat16 h; short s; } u; u.h = h; return u.s;
}

// async 16B global -> LDS (lane i lands at lds_base + i*16; lds ptr must be wave-uniform)
__device__ __forceinline__ void async_copy16(const short* g, short* l) {
  __builtin_amdgcn_global_load_lds((const __attribute__((address_space(1))) void*)g,
                                   (__attribute__((address_space(3))) void*)l, 16, 0, 0);
}

// ---------------- fp32 -> bf16 elementwise (x) ----------------
__global__ __launch_bounds__(256) void cvt_kernel(const float* __restrict__ in,
                                                  short* __restrict__ out, int n4) {
  const int i = blockIdx.x * 256 + threadIdx.x;
  if (i >= n4) return;
  const float4 v = ((const float4*)in)[i];
  short4v o;
  o[0] = f2b(v.x); o[1] = f2b(v.y); o[2] = f2b(v.z); o[3] = f2b(v.w);
  ((short4v*)out)[i] = o;
}

// ---------------- fp32 [R][Cn] -> bf16 transposed [Cn][R] ----------------
__global__ __launch_bounds__(256) void tcvt_kernel(const float* __restrict__ in,
                                                   short* __restrict__ out, int R, int Cn,
                                                   int qscale_rows, float qscale) {
  __shared__ float t[32][33];
  const int tx = threadIdx.x, ty = threadIdx.y;
  const int c0 = blockIdx.x * 32, r0 = blockIdx.y * 32;
#pragma unroll
  for (int yy = 0; yy < 32; yy += 8)
    t[ty + yy][tx] = in[(size_t)(r0 + ty + yy) * Cn + (c0 + tx)];
  __syncthreads();
#pragma unroll
  for (int yy = 0; yy < 32; yy += 8) {
    const int orow = c0 + ty + yy;
    float v = t[tx][ty + yy];
    if (orow < qscale_rows) v *= qscale;
    out[(size_t)orow * R + (r0 + tx)] = f2b(v);
  }
}

// ---------------- V transpose: qkv V-block [b][t][h*64+d] -> vT[(b*16+h)*64+d][t] ----------------
__global__ __launch_bounds__(256) void vtrans_kernel(const short* __restrict__ qkv,
                                                     short* __restrict__ vT) {
  constexpr int T = 2048, C3 = 3072, HD = 64;
  const int bh = blockIdx.y, b = bh >> 4, h = bh & 15;
  const int t0 = blockIdx.x * 64;
  __shared__ short tile[64][72];
  const int tid = threadIdx.x;
  const int tr = tid >> 2, dc = (tid & 3) * 16;
  const short* src = qkv + (size_t)b * T * C3 + (size_t)(t0 + tr) * C3 + 2048 + h * HD + dc;
  *(bf16x8*)&tile[tr][dc] = *(const bf16x8*)src;
  *(bf16x8*)&tile[tr][dc + 8] = *(const bf16x8*)(src + 8);
  __syncthreads();
  const int dr = tid >> 2, tc = (tid & 3) * 16;
  bf16x8 o0, o1;
#pragma unroll
  for (int i = 0; i < 8; i++) o0[i] = tile[tc + i][dr];
#pragma unroll
  for (int i = 0; i < 8; i++) o1[i] = tile[tc + 8 + i][dr];
  short* dst = vT + ((size_t)bh * HD + dr) * T + t0 + tc;
  *(bf16x8*)dst = o0;
  *(bf16x8*)(dst + 8) = o1;
}

// ---------------- C[M,N] = A[M,K] * Bt[N,K]^T  (bf16 in, OutT out) ----------------
// XCD-aware swizzle: flat%8 ~ XCD; give each XCD a contiguous 16(bm)-tall rectangle
// so its 4 MB L2 holds the A/B strips (~7 MB vs ~22 MB full working set).
template <typename OutT>
__global__ __launch_bounds__(256) void gemm_bt_kernel(const short* __restrict__ A,
                                                      const short* __restrict__ Bt,
                                                      OutT* __restrict__ C,
                                                      int M, int N, int K) {
  __shared__ short As[128 * 32];
  __shared__ short Bs[128 * 32];
  const int tid = threadIdx.x;
  const int lane = tid & 63, wave = tid >> 6;
  const int quad = lane >> 4, l16 = lane & 15;

  // block swizzle (ny must be multiple of 16, nb multiple of 8 — true for both GEMMs)
  const int nx = gridDim.x, ny = gridDim.y;
  const int nb = nx * ny, chunk = nb >> 3;
  const int flat = blockIdx.y * nx + blockIdx.x;
  const int nf = (flat & 7) * chunk + (flat >> 3);
  const int per_srow = 16 * nx;
  const int srw = nf / per_srow, idx = nf % per_srow;
  const int bm = srw * 16 + (idx & 15);
  const int bn = idx >> 4;
  const int m0 = bm * 128, n0 = bn * 128;
  const int wm = (wave >> 1) * 64, wn = (wave & 1) * 64;

  f32x4 acc[4][4] = {};

  const int lrow = wave * 32 + (lane >> 2);
  const int lcol = (lane & 3) * 8;
  const short* ga0 = A + (size_t)(m0 + lrow) * K + lcol;
  const short* ga1 = A + (size_t)(m0 + lrow + 16) * K + lcol;
  const short* gb0 = Bt + (size_t)(n0 + lrow) * K + lcol;
  const short* gb1 = Bt + (size_t)(n0 + lrow + 16) * K + lcol;
  short* la0 = &As[(wave * 2 + 0) * 512];
  short* la1 = &As[(wave * 2 + 1) * 512];
  short* lb0 = &Bs[(wave * 2 + 0) * 512];
  short* lb1 = &Bs[(wave * 2 + 1) * 512];

  for (int kt = 0; kt < K; kt += 32) {
    __syncthreads();
    async_copy16(ga0 + kt, la0);
    async_copy16(ga1 + kt, la1);
    async_copy16(gb0 + kt, lb0);
    async_copy16(gb1 + kt, lb1);
    __syncthreads();
    bf16x8 af[4], bfr[4];
#pragma unroll
    for (int mt = 0; mt < 4; mt++)
      af[mt] = *(const bf16x8*)&As[(wm + mt * 16 + l16) * 32 + quad * 8];
#pragma unroll
    for (int nt = 0; nt < 4; nt++)
      bfr[nt] = *(const bf16x8*)&Bs[(wn + nt * 16 + l16) * 32 + quad * 8];
#pragma unroll
    for (int mt = 0; mt < 4; mt++)
#pragma unroll
      for (int nt = 0; nt < 4; nt++)
        acc[mt][nt] = __builtin_amdgcn_mfma_f32_16x16x32_bf16(af[mt], bfr[nt], acc[mt][nt], 0, 0, 0);
  }

#pragma unroll
  for (int mt = 0; mt < 4; mt++)
#pragma unroll
    for (int nt = 0; nt < 4; nt++) {
      const int col = n0 + wn + nt * 16 + l16;
#pragma unroll
      for (int r = 0; r < 4; r++) {
        const int row = m0 + wm + mt * 16 + quad * 4 + r;
        const float v = acc[mt][nt][r];
        if constexpr (sizeof(OutT) == 4) {
          C[(size_t)row * N + col] = v;
        } else {
          C[(size_t)row * N + col] = f2b(v);
        }
      }
    }
}

// ---------------- causal flash attention, 128-row Q-tiles, pipelined ----------------
// grid (8, B*H), block 256 = 4 waves; block x handles 128-row qtiles {15-x, x}.
// Per wave: 32 q-rows (two 16-row subtiles) sharing one K/V fragment set per iter.
// Fixed-base softmax (bounded logits -> p=exp2(s), no running max; partials additive).
// Pipeline: double-buffered Ks/Vt, ONE barrier per iter; next tile's global loads
// issued right after the barrier and consumed at the NEXT iter's ds_write, so
// global latency hides behind a full compute section. jmax=2t+1 is odd, so buffer
// parity flips across halves without an extra barrier (see ordering argument R8).
__global__ __launch_bounds__(256, 2) void attn_kernel(const short* __restrict__ qkv,
                                                      const short* __restrict__ vT,
                                                      short* __restrict__ y) {
  constexpr int T = 2048, C3 = 3072, Cc = 1024, HD = 64;
  constexpr int KS = 68;
  const int bh = blockIdx.y, b = bh >> 4, h = bh & 15;
  const int tid = threadIdx.x, lane = tid & 63, wave = tid >> 6;
  const int quad = lane >> 4, l16 = lane & 15;

  __shared__ short Ksb[2][64 * KS];    // [buf][kv][d]
  __shared__ short Vtb[2][64 * KS];    // [buf][d][kv]
  __shared__ short Ps[4][2][16 * KS];  // per-wave, per-subtile P [q][kv]

  const size_t base = (size_t)b * T * C3;
  const int qcol = h * HD, kcol = Cc + h * HD;
  const size_t vtbase = (size_t)bh * HD * T;
  const int srow = tid >> 2;        // 0..63
  const int sc0 = (tid & 3) * 16;   // 0,16,32,48

  const short* kstage = qkv + base + (size_t)srow * C3 + kcol + sc0;  // + kv0*C3
  const short* vstage = vT + vtbase + (size_t)srow * T + sc0;         // + kv0

  bf16x8 ones;
#pragma unroll
  for (int i = 0; i < 8; i++) ones[i] = (short)0x3F80;  // bf16 1.0

  for (int half = 0; half < 2; half++) {
    const int t = half ? blockIdx.x : (15 - blockIdx.x);
    const int q0 = t * 128;
    const int jmax = 2 * t + 1;

    // Q fragments, both subtiles (A-layout: m=l16, k=quad*8+j)
    bf16x8 qf[2][2];
#pragma unroll
    for (int s = 0; s < 2; s++) {
      const short* qp = qkv + base + (size_t)(q0 + s * 64 + wave * 16 + l16) * C3 + qcol + quad * 8;
      qf[s][0] = *(const bf16x8*)qp;
      qf[s][1] = *(const bf16x8*)(qp + 32);
    }

    f32x4 o[2][4] = {};
    f32x4 l[2] = {};

    // prologue: prefetch tile 0 into registers
    bf16x8 kr0, kr1, vr0, vr1;
    {
      const short* kp = kstage;
      kr0 = *(const bf16x8*)kp; kr1 = *(const bf16x8*)(kp + 8);
      const short* vp = vstage;
      vr0 = *(const bf16x8*)vp; vr1 = *(const bf16x8*)(vp + 8);
    }

    for (int j = 0; j <= jmax; j++) {
      const int cur = j & 1;
      // stage prefetched tile j (implicit vmcnt wait on kr/vr here)
      {
        short* kd = &Ksb[cur][srow * KS + sc0];
        *(bf16x8*)kd = kr0; *(bf16x8*)(kd + 8) = kr1;
        short* vd = &Vtb[cur][srow * KS + sc0];
        *(bf16x8*)vd = vr0; *(bf16x8*)(vd + 8) = vr1;
      }
      __syncthreads();  // tile j visible; also orders vs reads of buf[cur] at iter j-2

      // issue next tile's global loads NOW — consumed at next iter's ds_write,
      // so they have the whole compute section below to complete
      if (j < jmax) {
        const int kv1 = (j + 1) * 64;
        const short* kp = kstage + (size_t)kv1 * C3;
        kr0 = *(const bf16x8*)kp; kr1 = *(const bf16x8*)(kp + 8);
        const short* vp = vstage + kv1;
        vr0 = *(const bf16x8*)vp; vr1 = *(const bf16x8*)(vp + 8);
      }

      // shared K/V fragments for both subtiles
      bf16x8 kf[4][2], vf[4][2];
#pragma unroll
      for (int nt = 0; nt < 4; nt++) {
        kf[nt][0] = *(const bf16x8*)&Ksb[cur][(nt * 16 + l16) * KS + quad * 8];
        kf[nt][1] = *(const bf16x8*)&Ksb[cur][(nt * 16 + l16) * KS + 32 + quad * 8];
        vf[nt][0] = *(const bf16x8*)&Vtb[cur][(nt * 16 + l16) * KS + quad * 8];
        vf[nt][1] = *(const bf16x8*)&Vtb[cur][(nt * 16 + l16) * KS + 32 + quad * 8];
      }

      const bool lo_act = (j < jmax);  // subtile 0 active while j <= 2t

#pragma unroll
      for (int s = 0; s < 2; s++) {
        if (s == 0 && !lo_act) continue;
        f32x4 sc[4];
#pragma unroll
        for (int nt = 0; nt < 4; nt++) {
          f32x4 a = {};
          a = __builtin_amdgcn_mfma_f32_16x16x32_bf16(qf[s][0], kf[nt][0], a, 0, 0, 0);
          a = __builtin_amdgcn_mfma_f32_16x16x32_bf16(qf[s][1], kf[nt][1], a, 0, 0, 0);
          sc[nt] = a;
        }
        const bool diag = (s == 0) ? (j == jmax - 1) : (j == jmax);
        if (diag) {
#pragma unroll
          for (int nt = 0; nt < 4; nt++)
#pragma unroll
            for (int r = 0; r < 4; r++) {
              const int row_l = wave * 16 + quad * 4 + r;
              const int col_l = nt * 16 + l16;
              if (col_l > row_l) sc[nt][r] = -INFINITY;
            }
        }
#pragma unroll
        for (int nt = 0; nt < 4; nt++)
#pragma unroll
          for (int r = 0; r < 4; r++)
            Ps[wave][s][(quad * 4 + r) * KS + nt * 16 + l16] =
                f2b(__builtin_amdgcn_exp2f(sc[nt][r]));
      }
      // wave-private Ps: wave-local drain (LDS completes out of order)
      asm volatile("s_waitcnt lgkmcnt(0)" ::: "memory");

#pragma unroll
      for (int s = 0; s < 2; s++) {
        if (s == 0 && !lo_act) continue;
        bf16x8 pa0 = *(const bf16x8*)&Ps[wave][s][l16 * KS + quad * 8];
        bf16x8 pa1 = *(const bf16x8*)&Ps[wave][s][l16 * KS + 32 + quad * 8];
        f32x4 lsum = {};
        lsum = __builtin_amdgcn_mfma_f32_16x16x32_bf16(pa0, ones, lsum, 0, 0, 0);
        lsum = __builtin_amdgcn_mfma_f32_16x16x32_bf16(pa1, ones, lsum, 0, 0, 0);
        l[s] += lsum;
#pragma unroll
        for (int nt = 0; nt < 4; nt++) {
          o[s][nt] = __builtin_amdgcn_mfma_f32_16x16x32_bf16(pa0, vf[nt][0], o[s][nt], 0, 0, 0);
          o[s][nt] = __builtin_amdgcn_mfma_f32_16x16x32_bf16(pa1, vf[nt][1], o[s][nt], 0, 0, 0);
        }
      }
    }

#pragma unroll
    for (int s = 0; s < 2; s++)
#pragma unroll
      for (int nt = 0; nt < 4; nt++)
#pragma unroll
        for (int r = 0; r < 4; r++) {
          const int row_g = q0 + s * 64 + wave * 16 + quad * 4 + r;
          y[(size_t)(b * T + row_g) * Cc + h * HD + nt * 16 + l16] = f2b(o[s][nt][r] / l[s][r]);
        }
  }
}

extern "C" void kernel_launch(void* const* d_in, const int* in_sizes, int n_in,
                              void* d_out, int out_size, void* d_ws, size_t ws_size,
                              hipStream_t stream) {
  constexpr int B = 4, T = 2048, C = 1024;
  constexpr int M = B * T;          // 8192
  constexpr int N1 = 3 * C;         // 3072
  const float* x      = (const float*)d_in[0];
  const float* w_attn = (const float*)d_in[1];
  const float* w_proj = (const float*)d_in[2];
  float* out = (float*)d_out;

  char* ws = (char*)d_ws;
  short* xb   = (short*)(ws + 0);                       // 16 MB (x bf16; reused as vT)
  short* waT  = (short*)(ws + 16777216);                // 6 MB
  short* wpT  = (short*)(ws + 23068672);                // 2 MB
  short* qkvb = (short*)(ws + 25165824);                // 48 MB
  short* yb   = (short*)(ws + 75497472);                // 16 MB
  short* vT   = xb;                                     // xb dead after qkv GEMM

  const float qscale = 0.125f * 1.44269504088896340736f;  // 1/sqrt(64) * log2(e)

  cvt_kernel<<<(M * C / 4 + 255) / 256, 256, 0, stream>>>(x, xb, M * C / 4);
  tcvt_kernel<<<dim3(N1 / 32, C / 32), dim3(32, 8), 0, stream>>>(w_attn, waT, C, N1, C, qscale);
  tcvt_kernel<<<dim3(C / 32, C / 32), dim3(32, 8), 0, stream>>>(w_proj, wpT, C, C, 0, 1.0f);
  gemm_bt_kernel<short><<<dim3(N1 / 128, M / 128), 256, 0, stream>>>(xb, waT, qkvb, M, N1, C);
  vtrans_kernel<<<dim3(T / 64, B * 16), 256, 0, stream>>>(qkvb, vT);
  attn_kernel<<<dim3(8, B * 16), 256, 0, stream>>>(qkvb, vT, yb);
  gemm_bt_kernel<float><<<dim3(C / 128, M / 128), 256, 0, stream>>>(yb, wpT, out, M, C, C);
}

// Round 9
// 270.255 us; speedup vs baseline: 1.0823x; 1.0823x over previous
//
#include <hip/hip_runtime.h>
#include <hip/hip_bf16.h>

typedef short bf16x8 __attribute__((ext_vector_type(8)));
typedef short short4v __attribute__((ext_vector_type(4)));
typedef float f32x4 __attribute__((ext_vector_type(4)));

__device__ __forceinline__ short f2b(float f) {
  __hip_bfloat16 h = __float2bfloat16(f);
  union { __hip_bfloat16 h; short s; } u; u.h = h; return u.s;
}

// async 16B global -> LDS DMA (lane i lands at lds_base + i*16; lds ptr wave-uniform)
__device__ __forceinline__ void async_copy16(const short* g, short* l) {
  __builtin_amdgcn_global_load_lds((const __attribute__((address_space(1))) void*)g,
                                   (__attribute__((address_space(3))) void*)l, 16, 0, 0);
}

// ---------------- fp32 -> bf16 elementwise (x) ----------------
__global__ __launch_bounds__(256) void cvt_kernel(const float* __restrict__ in,
                                                  short* __restrict__ out, int n4) {
  const int i = blockIdx.x * 256 + threadIdx.x;
  if (i >= n4) return;
  const float4 v = ((const float4*)in)[i];
  short4v o;
  o[0] = f2b(v.x); o[1] = f2b(v.y); o[2] = f2b(v.z); o[3] = f2b(v.w);
  ((short4v*)out)[i] = o;
}

// ---------------- fp32 [R][Cn] -> bf16 transposed [Cn][R] ----------------
__global__ __launch_bounds__(256) void tcvt_kernel(const float* __restrict__ in,
                                                   short* __restrict__ out, int R, int Cn,
                                                   int qscale_rows, float qscale) {
  __shared__ float t[32][33];
  const int tx = threadIdx.x, ty = threadIdx.y;
  const int c0 = blockIdx.x * 32, r0 = blockIdx.y * 32;
#pragma unroll
  for (int yy = 0; yy < 32; yy += 8)
    t[ty + yy][tx] = in[(size_t)(r0 + ty + yy) * Cn + (c0 + tx)];
  __syncthreads();
#pragma unroll
  for (int yy = 0; yy < 32; yy += 8) {
    const int orow = c0 + ty + yy;
    float v = t[tx][ty + yy];
    if (orow < qscale_rows) v *= qscale;
    out[(size_t)orow * R + (r0 + tx)] = f2b(v);
  }
}

// ---------------- V transpose: qkv V-block [b][t][h*64+d] -> vT[(b*16+h)*64+d][t] ----------------
__global__ __launch_bounds__(256) void vtrans_kernel(const short* __restrict__ qkv,
                                                     short* __restrict__ vT) {
  constexpr int T = 2048, C3 = 3072, HD = 64;
  const int bh = blockIdx.y, b = bh >> 4, h = bh & 15;
  const int t0 = blockIdx.x * 64;
  __shared__ short tile[64][72];
  const int tid = threadIdx.x;
  const int tr = tid >> 2, dc = (tid & 3) * 16;
  const short* src = qkv + (size_t)b * T * C3 + (size_t)(t0 + tr) * C3 + 2048 + h * HD + dc;
  *(bf16x8*)&tile[tr][dc] = *(const bf16x8*)src;
  *(bf16x8*)&tile[tr][dc + 8] = *(const bf16x8*)(src + 8);
  __syncthreads();
  const int dr = tid >> 2, tc = (tid & 3) * 16;
  bf16x8 o0, o1;
#pragma unroll
  for (int i = 0; i < 8; i++) o0[i] = tile[tc + i][dr];
#pragma unroll
  for (int i = 0; i < 8; i++) o1[i] = tile[tc + 8 + i][dr];
  short* dst = vT + ((size_t)bh * HD + dr) * T + t0 + tc;
  *(bf16x8*)dst = o0;
  *(bf16x8*)(dst + 8) = o1;
}

// ---------------- C[M,N] = A[M,K] * Bt[N,K]^T  (bf16 in, OutT out) ----------------
template <typename OutT>
__global__ __launch_bounds__(256) void gemm_bt_kernel(const short* __restrict__ A,
                                                      const short* __restrict__ Bt,
                                                      OutT* __restrict__ C,
                                                      int M, int N, int K) {
  __shared__ short As[128 * 32];
  __shared__ short Bs[128 * 32];
  const int tid = threadIdx.x;
  const int lane = tid & 63, wave = tid >> 6;
  const int quad = lane >> 4, l16 = lane & 15;

  // XCD-aware swizzle (neutral at current sizes, kept for L2 locality)
  const int nx = gridDim.x, ny = gridDim.y;
  const int nb = nx * ny, chunk = nb >> 3;
  const int flat = blockIdx.y * nx + blockIdx.x;
  const int nf = (flat & 7) * chunk + (flat >> 3);
  const int per_srow = 16 * nx;
  const int srw = nf / per_srow, idx = nf % per_srow;
  const int bm = srw * 16 + (idx & 15);
  const int bn = idx >> 4;
  const int m0 = bm * 128, n0 = bn * 128;
  const int wm = (wave >> 1) * 64, wn = (wave & 1) * 64;

  f32x4 acc[4][4] = {};

  const int lrow = wave * 32 + (lane >> 2);
  const int lcol = (lane & 3) * 8;
  const short* ga0 = A + (size_t)(m0 + lrow) * K + lcol;
  const short* ga1 = A + (size_t)(m0 + lrow + 16) * K + lcol;
  const short* gb0 = Bt + (size_t)(n0 + lrow) * K + lcol;
  const short* gb1 = Bt + (size_t)(n0 + lrow + 16) * K + lcol;
  short* la0 = &As[(wave * 2 + 0) * 512];
  short* la1 = &As[(wave * 2 + 1) * 512];
  short* lb0 = &Bs[(wave * 2 + 0) * 512];
  short* lb1 = &Bs[(wave * 2 + 1) * 512];

  for (int kt = 0; kt < K; kt += 32) {
    __syncthreads();
    async_copy16(ga0 + kt, la0);
    async_copy16(ga1 + kt, la1);
    async_copy16(gb0 + kt, lb0);
    async_copy16(gb1 + kt, lb1);
    __syncthreads();
    bf16x8 af[4], bfr[4];
#pragma unroll
    for (int mt = 0; mt < 4; mt++)
      af[mt] = *(const bf16x8*)&As[(wm + mt * 16 + l16) * 32 + quad * 8];
#pragma unroll
    for (int nt = 0; nt < 4; nt++)
      bfr[nt] = *(const bf16x8*)&Bs[(wn + nt * 16 + l16) * 32 + quad * 8];
#pragma unroll
    for (int mt = 0; mt < 4; mt++)
#pragma unroll
      for (int nt = 0; nt < 4; nt++)
        acc[mt][nt] = __builtin_amdgcn_mfma_f32_16x16x32_bf16(af[mt], bfr[nt], acc[mt][nt], 0, 0, 0);
  }

#pragma unroll
  for (int mt = 0; mt < 4; mt++)
#pragma unroll
    for (int nt = 0; nt < 4; nt++) {
      const int col = n0 + wn + nt * 16 + l16;
#pragma unroll
      for (int r = 0; r < 4; r++) {
        const int row = m0 + wm + mt * 16 + quad * 4 + r;
        const float v = acc[mt][nt][r];
        if constexpr (sizeof(OutT) == 4) {
          C[(size_t)row * N + col] = v;
        } else {
          C[(size_t)row * N + col] = f2b(v);
        }
      }
    }
}

// ---------------- causal flash attention: 128-row Q-tiles, DMA double-buffer ----------------
// grid (8, B*H), block 256 = 4 waves; block x handles 128-row qtiles {15-x, x}.
// Per wave: 32 q-rows (two 16-row subtiles) sharing one K/V fragment set per iter.
// Fixed-base softmax (bounded logits -> p=exp2(s) exactly, partials additive).
// ONE barrier per iter: global_load_lds DMA for tile j+1 into buf[cur^1] is issued
// right after the barrier; the NEXT iteration's barrier (implicit vmcnt(0)) drains
// it after a full compute section — latency hidden, no VGPRs held (R8's reg-prefetch
// failure mode). DMA forbids padded LDS (lane->base+16i fixed), so Ks/Vt are
// unpadded stride-64 with XOR swizzle: row r, 16B-chunk c stored at chunk c^(r&7).
// Per-lane *global* addresses are permuted to produce this (coalescing preserved:
// each 8-lane group covers one full 128B row); b128 frag reads then hit 2 lanes per
// 4-bank group = conflict-free.
__global__ __launch_bounds__(256, 2) void attn_kernel(const short* __restrict__ qkv,
                                                      const short* __restrict__ vT,
                                                      short* __restrict__ y) {
  constexpr int T = 2048, C3 = 3072, Cc = 1024, HD = 64;
  const int bh = blockIdx.y, b = bh >> 4, h = bh & 15;
  const int tid = threadIdx.x, lane = tid & 63, wave = tid >> 6;
  const int quad = lane >> 4, l16 = lane & 15;

  __shared__ short Ksb[2][64 * 64];    // [buf][kv][d], XOR-swizzled chunks
  __shared__ short Vtb[2][64 * 64];    // [buf][d][kv], XOR-swizzled chunks
  __shared__ short Ps[4][2][16 * 68];  // per-wave, per-subtile P [q][kv], padded

  const size_t base = (size_t)b * T * C3;
  const int qcol = h * HD, kcol = Cc + h * HD;
  const size_t vtbase = (size_t)bh * HD * T;

  // DMA source pointers: lane i of instr t covers tile row wave*16+t*8+(i>>3),
  // global chunk (i&7)^(i>>3)  (so LDS chunk i&7 holds global chunk (i&7)^(r&7))
  const int r8 = lane >> 3;
  const int cg8 = ((lane & 7) ^ r8) * 8;
  const short* gk[2];
  const short* gv[2];
  short* lk[2][2]; short* lv[2][2];
#pragma unroll
  for (int t8 = 0; t8 < 2; t8++) {
    const int row = wave * 16 + t8 * 8 + r8;
    gk[t8] = qkv + base + (size_t)row * C3 + kcol + cg8;
    gv[t8] = vT + vtbase + (size_t)row * T + cg8;
#pragma unroll
    for (int bu = 0; bu < 2; bu++) {
      lk[bu][t8] = &Ksb[bu][(wave * 16 + t8 * 8) * 64];
      lv[bu][t8] = &Vtb[bu][(wave * 16 + t8 * 8) * 64];
    }
  }
  // frag-read swizzled chunk offsets (shorts): logical chunk ks*4+quad, row parity l16&7
  const int sw0 = ((quad) ^ (l16 & 7)) * 8;
  const int sw1 = ((quad + 4) ^ (l16 & 7)) * 8;

  bf16x8 ones;
#pragma unroll
  for (int i = 0; i < 8; i++) ones[i] = (short)0x3F80;  // bf16 1.0

  for (int half = 0; half < 2; half++) {
    const int t = half ? blockIdx.x : (15 - blockIdx.x);
    const int q0 = t * 128;
    const int jmax = 2 * t + 1;

    // Q fragments, both subtiles (A-layout: m=l16, k=quad*8+j)
    bf16x8 qf[2][2];
#pragma unroll
    for (int s = 0; s < 2; s++) {
      const short* qp = qkv + base + (size_t)(q0 + s * 64 + wave * 16 + l16) * C3 + qcol + quad * 8;
      qf[s][0] = *(const bf16x8*)qp;
      qf[s][1] = *(const bf16x8*)(qp + 32);
    }

    f32x4 o[2][4] = {};
    f32x4 l[2] = {};

    // prologue: DMA tile 0 into buf 0 (drained by the loop's first barrier)
    async_copy16(gk[0], lk[0][0]);
    async_copy16(gk[1], lk[0][1]);
    async_copy16(gv[0], lv[0][0]);
    async_copy16(gv[1], lv[0][1]);

    for (int j = 0; j <= jmax; j++) {
      const int cur = j & 1;
      __syncthreads();  // drains vmcnt: tile j staged in buf[cur]; all waves past buf[cur^1] reads

      // issue tile j+1 DMA now — a full compute section before its drain
      if (j < jmax) {
        const size_t ko = (size_t)(j + 1) * 64 * C3;
        const int vo = (j + 1) * 64;
        async_copy16(gk[0] + ko, lk[cur ^ 1][0]);
        async_copy16(gk[1] + ko, lk[cur ^ 1][1]);
        async_copy16(gv[0] + vo, lv[cur ^ 1][0]);
        async_copy16(gv[1] + vo, lv[cur ^ 1][1]);
      }

      // shared K/V fragments for both subtiles (swizzled addressing)
      bf16x8 kf[4][2], vf[4][2];
#pragma unroll
      for (int nt = 0; nt < 4; nt++) {
        const int rowb = (nt * 16 + l16) * 64;
        kf[nt][0] = *(const bf16x8*)&Ksb[cur][rowb + sw0];
        kf[nt][1] = *(const bf16x8*)&Ksb[cur][rowb + sw1];
        vf[nt][0] = *(const bf16x8*)&Vtb[cur][rowb + sw0];
        vf[nt][1] = *(const bf16x8*)&Vtb[cur][rowb + sw1];
      }

      const bool lo_act = (j < jmax);  // subtile 0 active while j <= 2t

#pragma unroll
      for (int s = 0; s < 2; s++) {
        if (s == 0 && !lo_act) continue;
        f32x4 sc[4];
#pragma unroll
        for (int nt = 0; nt < 4; nt++) {
          f32x4 a = {};
          a = __builtin_amdgcn_mfma_f32_16x16x32_bf16(qf[s][0], kf[nt][0], a, 0, 0, 0);
          a = __builtin_amdgcn_mfma_f32_16x16x32_bf16(qf[s][1], kf[nt][1], a, 0, 0, 0);
          sc[nt] = a;
        }
        const bool diag = (s == 0) ? (j == jmax - 1) : (j == jmax);
        if (diag) {
#pragma unroll
          for (int nt = 0; nt < 4; nt++)
#pragma unroll
            for (int r = 0; r < 4; r++) {
              const int row_l = wave * 16 + quad * 4 + r;
              const int col_l = nt * 16 + l16;
              if (col_l > row_l) sc[nt][r] = -INFINITY;
            }
        }
#pragma unroll
        for (int nt = 0; nt < 4; nt++)
#pragma unroll
          for (int r = 0; r < 4; r++)
            Ps[wave][s][(quad * 4 + r) * 68 + nt * 16 + l16] =
                f2b(__builtin_amdgcn_exp2f(sc[nt][r]));
      }
      // wave-private Ps: wave-local drain (LDS completes out of order)
      asm volatile("s_waitcnt lgkmcnt(0)" ::: "memory");

#pragma unroll
      for (int s = 0; s < 2; s++) {
        if (s == 0 && !lo_act) continue;
        bf16x8 pa0 = *(const bf16x8*)&Ps[wave][s][l16 * 68 + quad * 8];
        bf16x8 pa1 = *(const bf16x8*)&Ps[wave][s][l16 * 68 + 32 + quad * 8];
        f32x4 lsum = {};
        lsum = __builtin_amdgcn_mfma_f32_16x16x32_bf16(pa0, ones, lsum, 0, 0, 0);
        lsum = __builtin_amdgcn_mfma_f32_16x16x32_bf16(pa1, ones, lsum, 0, 0, 0);
        l[s] += lsum;
#pragma unroll
        for (int nt = 0; nt < 4; nt++) {
          o[s][nt] = __builtin_amdgcn_mfma_f32_16x16x32_bf16(pa0, vf[nt][0], o[s][nt], 0, 0, 0);
          o[s][nt] = __builtin_amdgcn_mfma_f32_16x16x32_bf16(pa1, vf[nt][1], o[s][nt], 0, 0, 0);
        }
      }
    }

#pragma unroll
    for (int s = 0; s < 2; s++)
#pragma unroll
      for (int nt = 0; nt < 4; nt++)
#pragma unroll
        for (int r = 0; r < 4; r++) {
          const int row_g = q0 + s * 64 + wave * 16 + quad * 4 + r;
          y[(size_t)(b * T + row_g) * Cc + h * HD + nt * 16 + l16] = f2b(o[s][nt][r] / l[s][r]);
        }
  }
}

extern "C" void kernel_launch(void* const* d_in, const int* in_sizes, int n_in,
                              void* d_out, int out_size, void* d_ws, size_t ws_size,
                              hipStream_t stream) {
  constexpr int B = 4, T = 2048, C = 1024;
  constexpr int M = B * T;          // 8192
  constexpr int N1 = 3 * C;         // 3072
  const float* x      = (const float*)d_in[0];
  const float* w_attn = (const float*)d_in[1];
  const float* w_proj = (const float*)d_in[2];
  float* out = (float*)d_out;

  char* ws = (char*)d_ws;
  short* xb   = (short*)(ws + 0);                       // 16 MB (x bf16; reused as vT)
  short* waT  = (short*)(ws + 16777216);                // 6 MB
  short* wpT  = (short*)(ws + 23068672);                // 2 MB
  short* qkvb = (short*)(ws + 25165824);                // 48 MB
  short* yb   = (short*)(ws + 75497472);                // 16 MB
  short* vT   = xb;                                     // xb dead after qkv GEMM

  const float qscale = 0.125f * 1.44269504088896340736f;  // 1/sqrt(64) * log2(e)

  cvt_kernel<<<(M * C / 4 + 255) / 256, 256, 0, stream>>>(x, xb, M * C / 4);
  tcvt_kernel<<<dim3(N1 / 32, C / 32), dim3(32, 8), 0, stream>>>(w_attn, waT, C, N1, C, qscale);
  tcvt_kernel<<<dim3(C / 32, C / 32), dim3(32, 8), 0, stream>>>(w_proj, wpT, C, C, 0, 1.0f);
  gemm_bt_kernel<short><<<dim3(N1 / 128, M / 128), 256, 0, stream>>>(xb, waT, qkvb, M, N1, C);
  vtrans_kernel<<<dim3(T / 64, B * 16), 256, 0, stream>>>(qkvb, vT);
  attn_kernel<<<dim3(8, B * 16), 256, 0, stream>>>(qkvb, vT, yb);
  gemm_bt_kernel<float><<<dim3(C / 128, M / 128), 256, 0, stream>>>(yb, wpT, out, M, C, C);
}